// Round 3
// baseline (723.029 us; speedup 1.0000x reference)
//
#include <hip/hip_runtime.h>
#include <hip/hip_bf16.h>

// Problem constants
#define S_LEN 4096
#define BATCH 16
#define DIM 1024
#define HDIM 512
#define LPOOL 32
#define NCOL (BATCH * DIM)      // 16384
#define NCOL4 (NCOL / 4)        // 4096
#define SCHUNK 64               // s-chunks for colsum
#define ROWS_PER_CHUNK (S_LEN / SCHUNK) // 64
#define LN_EPS 1e-5f

__device__ __forceinline__ float gelu_exact(float x) {
    return 0.5f * x * (1.0f + erff(x * 0.70710678118654752440f));
}

__device__ __forceinline__ float dot4(float4 a, float4 b) {
    return a.x * b.x + a.y * b.y + a.z * b.z + a.w * b.w;
}

// sum across 64 lanes, result on lane 0
__device__ __forceinline__ float wave_reduce_sum(float v) {
    #pragma unroll
    for (int off = 32; off > 0; off >>= 1) v += __shfl_down(v, off);
    return v;
}

// sum across 64 lanes, result on ALL lanes (butterfly)
__device__ __forceinline__ float wave_allreduce_sum(float v) {
    #pragma unroll
    for (int off = 32; off > 0; off >>= 1) v += __shfl_xor(v, off);
    return v;
}

// ---------------------------------------------------------------------------
// K1: partial column sums of features: part[sc][c] = sum over 64 s rows
__global__ void __launch_bounds__(256) k_colsum(const float* __restrict__ f,
                                                float* __restrict__ part) {
    int cb = blockIdx.x;          // 0..15
    int sc = blockIdx.y;          // 0..63
    int t  = threadIdx.x;
    int c4 = cb * 256 + t;        // float4 column index, < 4096
    const float4* f4 = (const float4*)f;
    float4 acc = make_float4(0.f, 0.f, 0.f, 0.f);
    int base = sc * ROWS_PER_CHUNK;
    #pragma unroll 4
    for (int i = 0; i < ROWS_PER_CHUNK; ++i) {
        float4 v = f4[(size_t)(base + i) * NCOL4 + c4];
        acc.x += v.x; acc.y += v.y; acc.z += v.z; acc.w += v.w;
    }
    ((float4*)part)[(size_t)sc * NCOL4 + c4] = acc;
}

// K2 (fused): blocks [0,64): context reduce; blocks [64,576): transpose w_rs1
// first half -> wT (1024 x 512). wT does NOT alias part.
__global__ void __launch_bounds__(256) k_prep(const float* __restrict__ part,
                                              float* __restrict__ context,
                                              const float* __restrict__ w,
                                              float* __restrict__ wT) {
    if (blockIdx.x < 64) {
        int c = blockIdx.x * 256 + threadIdx.x; // < 16384
        float s = 0.f;
        #pragma unroll 8
        for (int k = 0; k < SCHUNK; ++k) s += part[(size_t)k * NCOL + c];
        context[c] = s * (1.0f / (float)S_LEN);
    } else {
        __shared__ float tile[32][33];
        int t = blockIdx.x - 64;           // 0..511
        int jt = (t & 15) * 32;            // over j (512)
        int dt = (t >> 4) * 32;            // over d (1024)
        int tx = threadIdx.x & 31, ty = threadIdx.x >> 5; // 32 x 8
        #pragma unroll
        for (int i = 0; i < 32; i += 8)
            tile[ty + i][tx] = w[(size_t)(jt + ty + i) * 2048 + dt + tx];
        __syncthreads();
        #pragma unroll
        for (int i = 0; i < 32; i += 8)
            wT[(size_t)(dt + ty + i) * 512 + jt + tx] = tile[tx][ty + i];
    }
}

// K3 (fused, weight-stationary): one wave per j-output.
//  wid < 512:  sph[b][j]  = gelu(ctx[b] . w_sp1[j] + b_sp1[j])
//  wid >= 512: cpart[b][j] = ctx[b] . w_rs1[j, 1024:2048] + b_rs1[j]
// grid 256 x 256 (1024 waves)
__global__ void __launch_bounds__(256) k_sph_cpart(const float* __restrict__ ctx,
                                                   const float* __restrict__ w_sp1,
                                                   const float* __restrict__ b_sp1,
                                                   const float* __restrict__ w_rs1,
                                                   const float* __restrict__ b_rs1,
                                                   float* __restrict__ sph,
                                                   float* __restrict__ cpart) {
    int wid = blockIdx.x * 4 + (threadIdx.x >> 6);
    int lane = threadIdx.x & 63;
    bool is_sph = (wid < 512);
    int j = is_sph ? wid : (wid - 512);
    const float4* w4 = is_sph ? (const float4*)(w_sp1 + (size_t)j * DIM)
                              : (const float4*)(w_rs1 + (size_t)j * 2048 + 1024);
    float acc[BATCH];
    #pragma unroll
    for (int b = 0; b < BATCH; ++b) acc[b] = 0.f;
    #pragma unroll
    for (int i = 0; i < 4; ++i) {
        float4 w = w4[lane + i * 64];
        #pragma unroll
        for (int b = 0; b < BATCH; ++b) {
            float4 x = ((const float4*)(ctx + (size_t)b * DIM))[lane + i * 64];
            acc[b] += dot4(w, x);
        }
    }
    #pragma unroll
    for (int b = 0; b < BATCH; ++b) acc[b] = wave_reduce_sum(acc[b]);
    if (lane == 0) {
        if (is_sph) {
            float bias = b_sp1[j];
            #pragma unroll
            for (int b = 0; b < BATCH; ++b)
                sph[b * HDIM + j] = gelu_exact(acc[b] + bias);
        } else {
            float bias = b_rs1[j];
            #pragma unroll
            for (int b = 0; b < BATCH; ++b)
                cpart[b * HDIM + j] = acc[b] + bias;
        }
    }
}

// K4: span weights: softmax over 3 of sp_h[b] . w_sp2[k] + b_sp2[k]
// grid 16, block 64
__global__ void k_span(const float* __restrict__ sph, const float* __restrict__ w2,
                       const float* __restrict__ b2, float* __restrict__ spanw) {
    int b = blockIdx.x, lane = threadIdx.x;
    float vals[3];
    #pragma unroll
    for (int k = 0; k < 3; ++k) {
        const float4* x4 = (const float4*)(sph + (size_t)b * HDIM);
        const float4* w4 = (const float4*)(w2 + (size_t)k * HDIM);
        float s = 0.f;
        #pragma unroll
        for (int i = 0; i < 2; ++i) {
            float4 a = x4[lane + i * 64], w = w4[lane + i * 64];
            s += dot4(a, w);
        }
        s = wave_reduce_sum(s);
        vals[k] = s;
    }
    if (lane == 0) {
        float l0 = vals[0] + b2[0], l1 = vals[1] + b2[1], l2 = vals[2] + b2[2];
        float m = fmaxf(l0, fmaxf(l1, l2));
        float e0 = expf(l0 - m), e1 = expf(l1 - m), e2 = expf(l2 - m);
        float inv = 1.0f / (e0 + e1 + e2);
        spanw[b * 3 + 0] = e0 * inv;
        spanw[b * 3 + 1] = e1 * inv;
        spanw[b * 3 + 2] = e2 * inv;
    }
}

// K5: h[p][l][b][j] = gelu(hist(p,l,b) . w_rs1[j,0:1024] + ctx_part[b][j])
// grid (64 = p*32+l, 4 = j-quarter), block 512 (8 waves, 2 b per wave)
__global__ void __launch_bounds__(512) k_poolh(const float* __restrict__ feat,
                                               const float* __restrict__ wT,
                                               const float* __restrict__ cpart,
                                               float* __restrict__ hws) {
    int pl = blockIdx.x;
    int p = pl >> 5, l = pl & 31;
    int jq = blockIdx.y;
    int s = (p == 0) ? (S_LEN - LPOOL + l) : (l * (S_LEN / 32));
    __shared__ float hist[BATCH * DIM]; // 64 KiB
    const float4* src4 = (const float4*)(feat + (size_t)s * NCOL);
    float4* h4 = (float4*)hist;
    #pragma unroll
    for (int i = 0; i < 8; ++i) h4[threadIdx.x + i * 512] = src4[threadIdx.x + i * 512];
    __syncthreads();
    int lane = threadIdx.x & 63;
    int b0 = (threadIdx.x >> 6) * 2;   // 8 waves x 2 batches
    int j0 = jq * 128 + lane * 2;
    float acc[2][2];
    #pragma unroll
    for (int k = 0; k < 2; ++k) {
        acc[k][0] = cpart[(b0 + k) * HDIM + j0];
        acc[k][1] = cpart[(b0 + k) * HDIM + j0 + 1];
    }
    #pragma unroll 4
    for (int d = 0; d < DIM; ++d) {
        float2 w = *(const float2*)&wT[(size_t)d * HDIM + j0];
        #pragma unroll
        for (int k = 0; k < 2; ++k) {
            float h = hist[(b0 + k) * DIM + d];
            acc[k][0] += h * w.x;
            acc[k][1] += h * w.y;
        }
    }
    #pragma unroll
    for (int k = 0; k < 2; ++k) {
        int b = b0 + k;
        float2 o = make_float2(gelu_exact(acc[k][0]), gelu_exact(acc[k][1]));
        *(float2*)&hws[(((size_t)pl) * BATCH + b) * HDIM + j0] = o;
    }
}

// K6: scores -> softmax(decay) -> pooled feat -> combined (scaled by span wt)
// grid 32 (p*16+b), block 256
__global__ void k_pool_finish(const float* __restrict__ feat, const float* __restrict__ hws,
                              const float* __restrict__ wrs2, const float* __restrict__ brs2,
                              const float* __restrict__ spanw, const float* __restrict__ dl,
                              const float* __restrict__ dg, float* __restrict__ combined) {
    int p = blockIdx.x >> 4, b = blockIdx.x & 15;
    int t = threadIdx.x, lane = t & 63, w = t >> 6;
    __shared__ float sc[LPOOL];
    __shared__ float wl[LPOOL];
    for (int li = w; li < LPOOL; li += 4) {
        const float4* h4 = (const float4*)(hws + (((size_t)(p * LPOOL + li)) * BATCH + b) * HDIM);
        const float4* w4 = (const float4*)wrs2;
        float s = 0.f;
        #pragma unroll
        for (int i = 0; i < 2; ++i) {
            float4 a = h4[lane + i * 64], ww = w4[lane + i * 64];
            s += dot4(a, ww);
        }
        s = wave_reduce_sum(s);
        if (lane == 0) sc[li] = s + brs2[0];
    }
    __syncthreads();
    if (t == 0) {
        float decay = (p == 0) ? dl[0] : dg[0];
        float lg[LPOOL];
        float m = -1e30f;
        #pragma unroll
        for (int li = 0; li < LPOOL; ++li) {
            lg[li] = sc[li] + logf(powf(decay, (float)(LPOOL - 1 - li)) + 1e-8f);
            m = fmaxf(m, lg[li]);
        }
        float sum = 0.f;
        #pragma unroll
        for (int li = 0; li < LPOOL; ++li) { lg[li] = expf(lg[li] - m); sum += lg[li]; }
        float inv = 1.0f / sum;
        #pragma unroll
        for (int li = 0; li < LPOOL; ++li) wl[li] = lg[li] * inv;
    }
    __syncthreads();
    float sw = spanw[b * 3 + 1 + p];
    float4 acc = make_float4(0.f, 0.f, 0.f, 0.f);
    for (int li = 0; li < LPOOL; ++li) {
        int s_idx = (p == 0) ? (S_LEN - LPOOL + li) : (li * (S_LEN / 32));
        float4 v = ((const float4*)(feat + ((size_t)s_idx * BATCH + b) * DIM))[t];
        float wv = wl[li];
        acc.x += wv * v.x; acc.y += wv * v.y; acc.z += wv * v.z; acc.w += wv * v.w;
    }
    acc.x *= sw; acc.y *= sw; acc.z *= sw; acc.w *= sw;
    ((float4*)(combined + (size_t)b * 2048 + p * DIM))[t] = acc;
}

// K7: ffout[b][j] = gelu(combined[b] . w_ff[j] + b_ff[j]); weight-stationary,
// one wave per j (K=2048). grid 256 x 256
__global__ void __launch_bounds__(256) k_ff(const float* __restrict__ comb,
                                            const float* __restrict__ wff,
                                            const float* __restrict__ bff,
                                            float* __restrict__ ffout) {
    int j = blockIdx.x * 4 + (threadIdx.x >> 6);  // < 1024
    int lane = threadIdx.x & 63;
    const float4* w4 = (const float4*)(wff + (size_t)j * 2048);
    float acc[BATCH];
    #pragma unroll
    for (int b = 0; b < BATCH; ++b) acc[b] = 0.f;
    #pragma unroll
    for (int i = 0; i < 8; ++i) {
        float4 w = w4[lane + i * 64];
        #pragma unroll
        for (int b = 0; b < BATCH; ++b) {
            float4 x = ((const float4*)(comb + (size_t)b * 2048))[lane + i * 64];
            acc[b] += dot4(w, x);
        }
    }
    #pragma unroll
    for (int b = 0; b < BATCH; ++b) acc[b] = wave_reduce_sum(acc[b]);
    if (lane == 0) {
        float bias = bff[j];
        #pragma unroll
        for (int b = 0; b < BATCH; ++b)
            ffout[b * DIM + j] = gelu_exact(acc[b] + bias);
    }
}

// K8: fused[b] = layernorm(ffout[b]) * g + b; wave-per-row, grid 4 x 256
__global__ void __launch_bounds__(256) k_ln_ff(const float* __restrict__ ffout,
                                               const float* __restrict__ g,
                                               const float* __restrict__ bb,
                                               float* __restrict__ fused) {
    int b = blockIdx.x * 4 + (threadIdx.x >> 6);  // < 16
    int lane = threadIdx.x & 63;
    const float4* row = (const float4*)ffout + (size_t)b * 256;
    float4 y[4];
    float s = 0.f, ss = 0.f;
    #pragma unroll
    for (int i = 0; i < 4; ++i) {
        float4 v = row[lane + i * 64];
        y[i] = v;
        s += v.x + v.y + v.z + v.w;
        ss += v.x * v.x + v.y * v.y + v.z * v.z + v.w * v.w;
    }
    s = wave_allreduce_sum(s);
    ss = wave_allreduce_sum(ss);
    float mu = s * (1.0f / DIM);
    float var = ss * (1.0f / DIM) - mu * mu;
    float rs = rsqrtf(var + LN_EPS);
    float4* orow = (float4*)fused + (size_t)b * 256;
    #pragma unroll
    for (int i = 0; i < 4; ++i) {
        float4 g4 = ((const float4*)g)[lane + i * 64];
        float4 b4 = ((const float4*)bb)[lane + i * 64];
        float4 o;
        o.x = (y[i].x - mu) * rs * g4.x + b4.x;
        o.y = (y[i].y - mu) * rs * g4.y + b4.y;
        o.z = (y[i].z - mu) * rs * g4.z + b4.z;
        o.w = (y[i].w - mu) * rs * g4.w + b4.w;
        orow[lane + i * 64] = o;
    }
}

// K9: fg[b][j] = fused[b][j] * sigmoid(fused[b] . w_gate[j] + b_gate[j])
// weight-stationary, one wave per j (K=1024). grid 256 x 256
__global__ void __launch_bounds__(256) k_gate(const float* __restrict__ fused,
                                              const float* __restrict__ wg,
                                              const float* __restrict__ bg,
                                              float* __restrict__ fg) {
    int j = blockIdx.x * 4 + (threadIdx.x >> 6);  // < 1024
    int lane = threadIdx.x & 63;
    const float4* w4 = (const float4*)(wg + (size_t)j * DIM);
    float acc[BATCH];
    #pragma unroll
    for (int b = 0; b < BATCH; ++b) acc[b] = 0.f;
    #pragma unroll
    for (int i = 0; i < 4; ++i) {
        float4 w = w4[lane + i * 64];
        #pragma unroll
        for (int b = 0; b < BATCH; ++b) {
            float4 x = ((const float4*)(fused + (size_t)b * DIM))[lane + i * 64];
            acc[b] += dot4(w, x);
        }
    }
    #pragma unroll
    for (int b = 0; b < BATCH; ++b) acc[b] = wave_reduce_sum(acc[b]);
    if (lane == 0) {
        float bias = bg[j];
        #pragma unroll
        for (int b = 0; b < BATCH; ++b) {
            float gv = 1.0f / (1.0f + expf(-(acc[b] + bias)));
            fg[b * DIM + j] = fused[b * DIM + j] * gv;
        }
    }
}

// K10: out[s,b,:] = layernorm(fg[b] + features[s,b]) * ln_g + ln_b; attn fill.
// wave-per-row (1024 floats = 64 lanes x 4 float4), no LDS, no barriers.
// grid 16384, block 256 (4 rows per block)
__global__ void __launch_bounds__(256) k_final(const float* __restrict__ feat,
                                               const float* __restrict__ fg,
                                               const float* __restrict__ g,
                                               const float* __restrict__ bb,
                                               float* __restrict__ out,
                                               float* __restrict__ attn) {
    int r = blockIdx.x * 4 + (threadIdx.x >> 6);  // row = s*16+b, < 65536
    int lane = threadIdx.x & 63;
    int b = r & 15;
    const float4* xrow = (const float4*)feat + (size_t)r * 256;
    const float4* frow = (const float4*)fg + (size_t)b * 256;
    float4 y[4];
    float s = 0.f, ss = 0.f;
    #pragma unroll
    for (int i = 0; i < 4; ++i) {
        float4 x = xrow[lane + i * 64];
        float4 f = frow[lane + i * 64];
        float4 v;
        v.x = x.x + f.x; v.y = x.y + f.y; v.z = x.z + f.z; v.w = x.w + f.w;
        y[i] = v;
        s += v.x + v.y + v.z + v.w;
        ss += v.x * v.x + v.y * v.y + v.z * v.z + v.w * v.w;
    }
    s = wave_allreduce_sum(s);
    ss = wave_allreduce_sum(ss);
    float mu = s * (1.0f / DIM);
    float var = ss * (1.0f / DIM) - mu * mu;
    float rs = rsqrtf(var + LN_EPS);
    float4* orow = (float4*)out + (size_t)r * 256;
    #pragma unroll
    for (int i = 0; i < 4; ++i) {
        float4 g4 = ((const float4*)g)[lane + i * 64];
        float4 b4 = ((const float4*)bb)[lane + i * 64];
        float4 o;
        o.x = (y[i].x - mu) * rs * g4.x + b4.x;
        o.y = (y[i].y - mu) * rs * g4.y + b4.y;
        o.z = (y[i].z - mu) * rs * g4.z + b4.z;
        o.w = (y[i].w - mu) * rs * g4.w + b4.w;
        orow[lane + i * 64] = o;
    }
    if (lane == 0) attn[r] = 1.0f / (float)S_LEN;
}

extern "C" void kernel_launch(void* const* d_in, const int* in_sizes, int n_in,
                              void* d_out, int out_size, void* d_ws, size_t ws_size,
                              hipStream_t stream) {
    const float* feat    = (const float*)d_in[0];
    const float* w_sp1   = (const float*)d_in[1];
    const float* b_sp1   = (const float*)d_in[2];
    const float* w_sp2   = (const float*)d_in[3];
    const float* b_sp2   = (const float*)d_in[4];
    const float* w_rs1   = (const float*)d_in[5];
    const float* b_rs1   = (const float*)d_in[6];
    const float* w_rs2   = (const float*)d_in[7];
    const float* b_rs2   = (const float*)d_in[8];
    const float* dl      = (const float*)d_in[9];
    const float* dg      = (const float*)d_in[10];
    const float* w_ff    = (const float*)d_in[11];
    const float* b_ff    = (const float*)d_in[12];
    const float* ln_ff_g = (const float*)d_in[13];
    const float* ln_ff_b = (const float*)d_in[14];
    const float* w_gate  = (const float*)d_in[15];
    const float* b_gate  = (const float*)d_in[16];
    const float* ln_g    = (const float*)d_in[17];
    const float* ln_b    = (const float*)d_in[18];

    float* out  = (float*)d_out;
    float* attn = out + (size_t)S_LEN * BATCH * DIM;

    float* ws = (float*)d_ws;
    float* part     = ws;                    // 1,048,576 floats (4 MB)
    float* wT       = ws + 1048576;          // 524,288 floats (no aliasing!)
    float* hws      = wT + 524288;           // 524,288 floats
    float* context  = hws + 524288;          // 16384
    float* sph      = context + 16384;       // 8192
    float* spanw    = sph + 8192;            // 48 (pad 64)
    float* cpart    = spanw + 64;            // 8192
    float* combined = cpart + 8192;          // 32768
    float* ffout    = combined + 32768;      // 16384
    float* fusedv   = ffout + 16384;         // 16384
    float* fgv      = fusedv + 16384;        // 16384

    k_colsum<<<dim3(16, 64), 256, 0, stream>>>(feat, part);
    k_prep<<<576, 256, 0, stream>>>(part, context, w_rs1, wT);
    k_sph_cpart<<<256, 256, 0, stream>>>(context, w_sp1, b_sp1, w_rs1, b_rs1, sph, cpart);
    k_span<<<16, 64, 0, stream>>>(sph, w_sp2, b_sp2, spanw);
    k_poolh<<<dim3(64, 4), 512, 0, stream>>>(feat, wT, cpart, hws);
    k_pool_finish<<<32, 256, 0, stream>>>(feat, hws, w_rs2, b_rs2, spanw, dl, dg, combined);
    k_ff<<<256, 256, 0, stream>>>(combined, w_ff, b_ff, ffout);
    k_ln_ff<<<4, 256, 0, stream>>>(ffout, ln_ff_g, ln_ff_b, fusedv);
    k_gate<<<256, 256, 0, stream>>>(fusedv, w_gate, b_gate, fgv);
    k_final<<<16384, 256, 0, stream>>>(feat, fgv, ln_g, ln_b, out, attn);
}